// Round 8
// baseline (54.319 us; speedup 1.0000x reference)
//
#include <hip/hip_runtime.h>

// CharacterCNN — f32 in/out, int32 ids.
//  A) prep_kernel: [blocks 0..447] split Ht/Hg (hi bf16) + P (hi+lo bf16)
//     into MFMA-fragment-linear layout; [blocks 448..451] conv pattern LUTs
//     -> monotone-u16-key tables.
//  B) cnn_kernel: 256 thr / 128 tokens per block, ZERO barriers. Each wave
//     owns 32 tokens end-to-end (2 sets of 16 rows): masks -> key-table conv
//     max (ReLU clamp) -> highway MFMA (weights read once per wave, reused
//     for both row-sets; in-place hw, af pinned) -> projection MFMA -> out.

typedef __attribute__((ext_vector_type(8))) __bf16 bf16x8;
typedef __attribute__((ext_vector_type(8))) unsigned short u16x8;
typedef __attribute__((ext_vector_type(4))) float f32x4;

// table element offsets (u16 units) within ws
#define LC1   0      // 3 x 32
#define LRAW2 96     // 9 x 64
#define LT2   672    // 16 x 64
#define LRAW3 1696   // 27 x 128
#define LT3LO 5152   // 16 x 128
#define LT3HI 7200   // 16 x 128
// bf16 weights start here (bytes, 16B aligned)
#define WOFFB 18944
#define WT   0        // Ht hi  (50176) frag-linear
#define WG   50176    // Hg hi  (50176)
#define WPHI 100352   // P hi   (14336)
#define WPLO 114688   // P lo   (14336)
#define NWTH 114688
#define WSPLIT_BLOCKS 448
#define LUT_BLOCKS 4

#define CROW 232      // cnn LDS row stride (bf16 elems)

__device__ __forceinline__ unsigned short keyf(float x) {
  __bf16 h = (__bf16)x;
  unsigned short b = __builtin_bit_cast(unsigned short, h);
  return (b & 0x8000) ? (unsigned short)~b : (unsigned short)(b | 0x8000);
}

__device__ __forceinline__ u16x8 kmax8(u16x8 a, u16x8 b) {
  return __builtin_elementwise_max(a, b);
}

__device__ __forceinline__ u16x8 splat8(unsigned short v) {
  u16x8 r = {v, v, v, v, v, v, v, v};
  return r;
}

__device__ __forceinline__ bf16x8 unmap8(u16x8 k) {
  union { u16x8 v; unsigned u[4]; } a; a.v = k;
  union { unsigned u[4]; bf16x8 v; } o;
#pragma unroll
  for (int i = 0; i < 4; i++) {
    unsigned kk = a.u[i];
    unsigned s = (kk & 0x80008000u) >> 15;
    o.u[i] = kk ^ ~(s * 0x7FFFu);
  }
  return o.v;
}

// keep a bf16x8 fragment pinned in registers (def comes from asm -> no LDS remat)
__device__ __forceinline__ bf16x8 pin8(bf16x8 v) {
  union { bf16x8 v; unsigned w[4]; } x; x.v = v;
  asm volatile("" : "+v"(x.w[0]), "+v"(x.w[1]), "+v"(x.w[2]), "+v"(x.w[3]) :: "memory");
  return x.v;
}

// frag index for W[col][k]: nf=col>>4, lr=col&15, kf=k>>5, kr=k&31
__device__ __forceinline__ int fidx224(int col, int k) {
  int nf = col >> 4, lr = col & 15, kf = k >> 5, kr = k & 31;
  int lane = lr + ((kr >> 3) << 4);
  return (((nf * 7 + kf) << 9) + lane * 8 + (kr & 7));
}

// ---------------- prep kernel: wsplit (blocks 0..447) + luts (448..451) ----
__global__ __launch_bounds__(256) void prep_kernel(
    const float* __restrict__ E,
    const float* __restrict__ W1, const float* __restrict__ b1,
    const float* __restrict__ W2, const float* __restrict__ b2,
    const float* __restrict__ W3, const float* __restrict__ b3,
    const float* __restrict__ HtW, const float* __restrict__ HgW,
    const float* __restrict__ PW,
    unsigned short* __restrict__ tab, __bf16* __restrict__ wsb)
{
  const int tid = threadIdx.x;
  if (blockIdx.x < WSPLIT_BLOCKS) {
    int idx = blockIdx.x * 256 + tid;
    if (idx < 50176) {
      int col = idx / 224, k = idx - col * 224;
      wsb[WT + fidx224(col, k)] = (__bf16)HtW[idx];
    } else if (idx < 100352) {
      int e = idx - 50176;
      int col = e / 224, k = e - col * 224;
      wsb[WG + fidx224(col, k)] = (__bf16)HgW[e];
    } else if (idx < NWTH) {
      int e = idx - 100352;
      int col = e / 224, k = e - col * 224;
      float w = PW[e];
      __bf16 hi = (__bf16)w;
      int f = fidx224(col, k);
      wsb[WPHI + f] = hi;
      wsb[WPLO + f] = (__bf16)(w - (float)hi);
    }
    return;
  }

  // ---- LUT part ----
  __shared__ float X[3][16];
  __shared__ float U1[3][32];
  __shared__ float U2[9][64];
  __shared__ float U3[27][128];
  const int gid = (blockIdx.x - WSPLIT_BLOCKS) * 256 + tid;
  const int gsz = LUT_BLOCKS * 256;
  if (tid < 48) { int s = tid >> 4, i = tid & 15; X[s][i] = (s == 0) ? 0.f : E[(s - 1) * 16 + i]; }
  __syncthreads();

  for (int idx = tid; idx < 96; idx += 256) {
    int s = idx >> 5, c = idx & 31;
    float acc = b1[c];
#pragma unroll
    for (int i = 0; i < 16; i++) acc += W1[c * 16 + i] * X[s][i];
    U1[s][c] = acc;
  }
  for (int idx = tid; idx < 576; idx += 256) {
    int p = idx >> 6, c = idx & 63;
    int sa = p / 3, sb = p % 3;
    float acc = b2[c];
#pragma unroll
    for (int i = 0; i < 16; i++)
      acc += W2[c * 32 + i * 2 + 0] * X[sa][i] + W2[c * 32 + i * 2 + 1] * X[sb][i];
    U2[p][c] = acc;
  }
  for (int idx = tid; idx < 3456; idx += 256) {
    int p = idx >> 7, c = idx & 127;
    int sa = p / 9, sb = (p / 3) % 3, sc = p % 3;
    float acc = b3[c];
#pragma unroll
    for (int i = 0; i < 16; i++)
      acc += W3[c * 48 + i * 3 + 0] * X[sa][i]
           + W3[c * 48 + i * 3 + 1] * X[sb][i]
           + W3[c * 48 + i * 3 + 2] * X[sc][i];
    U3[p][c] = acc;
  }
  __syncthreads();

  for (int idx = gid; idx < 96; idx += gsz) {
    int r = idx >> 5, c = idx & 31;
    float v = (r == 0) ? fmaxf(U1[1][c], U1[2][c]) : U1[r][c];
    tab[LC1 + idx] = keyf(v);
  }
  for (int idx = gid; idx < 576; idx += gsz) tab[LRAW2 + idx] = keyf(U2[idx >> 6][idx & 63]);
  for (int idx = gid; idx < 3456; idx += gsz) tab[LRAW3 + idx] = keyf(U3[idx >> 7][idx & 127]);
  for (int idx = gid; idx < 1024; idx += gsz) {
    int s = idx >> 6, c = idx & 63;
    unsigned short k = 0;
#pragma unroll
    for (int b = 0; b < 4; b++)
      if ((s >> b) & 1) { unsigned short kb = keyf(U2[4 + 3 * (b >> 1) + (b & 1)][c]); if (kb > k) k = kb; }
    tab[LT2 + idx] = k;
  }
  for (int idx = gid; idx < 2048; idx += gsz) {
    int s = idx >> 7, c = idx & 127;
    unsigned short k = 0;
#pragma unroll
    for (int b = 0; b < 4; b++)
      if ((s >> b) & 1) { unsigned short kb = keyf(U3[13 + 3 * (b >> 1) + (b & 1)][c]); if (kb > k) k = kb; }
    tab[LT3LO + idx] = k;
    k = 0;
#pragma unroll
    for (int b = 0; b < 4; b++)
      if ((s >> b) & 1) { unsigned short kb = keyf(U3[22 + 3 * (b >> 1) + (b & 1)][c]); if (kb > k) k = kb; }
    tab[LT3HI + idx] = k;
  }
}

// ------------- cnn kernel: barrier-free, 32 tokens per wave -------------
__global__ __launch_bounds__(256) void cnn_kernel(
    const int* __restrict__ ids,
    const unsigned short* __restrict__ tab, const __bf16* __restrict__ wsb,
    const float* __restrict__ Htb, const float* __restrict__ Hgb,
    const float* __restrict__ Pb,
    float* __restrict__ out, int n_tok)
{
  __shared__ __attribute__((aligned(16))) __bf16 cnn[128 * CROW];
  __shared__ unsigned masks[128][2];

  const int tid = threadIdx.x;
  const int wave = tid >> 6, lane = tid & 63;
  const int tok0 = blockIdx.x * 128;
  const int rbase = wave * 32;

  // ---- masks: lanes 0..31 compute own wave's 32 tokens ----
  if (lane < 32) {
    int row = rbase + lane;
    unsigned mw = 0, mb = 0;
    if (tok0 + row < n_tok) {
      const int4* idp4 = (const int4*)(ids + (size_t)(tok0 + row) * 20);
      int st[22]; st[0] = 0; st[21] = 0;
#pragma unroll
      for (int q = 0; q < 5; q++) {
        int4 v = idp4[q];
        st[q * 4 + 1] = v.x + 1; st[q * 4 + 2] = v.y + 1;
        st[q * 4 + 3] = v.z + 1; st[q * 4 + 4] = v.w + 1;
      }
      unsigned m3i = 0, m2i = 0, mchar = 0;
#pragma unroll
      for (int l = 1; l <= 18; l++) m3i |= 1u << ((st[l] - 1) * 4 + (st[l + 1] - 1) * 2 + (st[l + 2] - 1));
#pragma unroll
      for (int l = 1; l <= 19; l++) m2i |= 1u << ((st[l] - 1) * 2 + (st[l + 1] - 1));
#pragma unroll
      for (int l = 1; l <= 20; l++) mchar |= 1u << (st[l] - 1);
      int sel = (mchar == 3u) ? 0 : ((mchar & 1u) ? 1 : 2);
      mw = m3i | (m2i << 8) | ((unsigned)sel << 12);
      mb = (unsigned)st[1] | ((unsigned)(st[20] * 3) << 4)
         | ((unsigned)(st[1] * 3 + st[2]) << 8) | ((unsigned)(st[19] * 9 + st[20] * 3) << 16);
    }
    masks[row][0] = mw; masks[row][1] = mb;
  }
  // same-wave LDS write->read: ordered by lgkmcnt, no barrier needed

  // ---- phase 1: wave fills its own 32 cnn rows ----
  const u16x8 KZ = splat8(0x8000);
#pragma unroll
  for (int s = 0; s < 2; s++) {
    const int tl = lane >> 2, q = lane & 3;
    const int row = rbase + s * 16 + tl;
    const unsigned mw = masks[row][0], mb = masks[row][1];
    const int sel = (mw >> 12) & 3;
    {
      u16x8 v = *(const u16x8*)(tab + LC1 + sel * 32 + q * 8);
      *(bf16x8*)&cnn[row * CROW + q * 8] = unmap8(kmax8(v, KZ));
    }
#pragma unroll
    for (int jj = 0; jj < 2; jj++) {
      int g = q + jj * 4;
      u16x8 v = *(const u16x8*)(tab + LT2 + ((mw >> 8) & 15) * 64 + g * 8);
      v = kmax8(v, *(const u16x8*)(tab + LRAW2 + (mb & 15) * 64 + g * 8));
      v = kmax8(v, *(const u16x8*)(tab + LRAW2 + ((mb >> 4) & 15) * 64 + g * 8));
      *(bf16x8*)&cnn[row * CROW + 32 + g * 8] = unmap8(kmax8(v, KZ));
    }
    const int m3 = mw & 255;
#pragma unroll
    for (int jj = 0; jj < 4; jj++) {
      int g = q + jj * 4;
      u16x8 v = kmax8(*(const u16x8*)(tab + LT3LO + (m3 & 15) * 128 + g * 8),
                      *(const u16x8*)(tab + LT3HI + ((m3 >> 4) & 15) * 128 + g * 8));
      v = kmax8(v, *(const u16x8*)(tab + LRAW3 + ((mb >> 8) & 15) * 128 + g * 8));
      v = kmax8(v, *(const u16x8*)(tab + LRAW3 + ((mb >> 16) & 31) * 128 + g * 8));
      *(bf16x8*)&cnn[row * CROW + 96 + g * 8] = unmap8(kmax8(v, KZ));
    }
  }

  // ---- phase 2: highway MFMA; weights read once, used for both row-sets ----
  const int lrow = lane & 15;
  const int kg8 = (lane >> 4) * 8;
  const int rr0 = (lane >> 4) * 4;

  bf16x8 af[2][7];
#pragma unroll
  for (int s = 0; s < 2; s++)
#pragma unroll
    for (int kf = 0; kf < 7; kf++)
      af[s][kf] = *(const bf16x8*)&cnn[(rbase + s * 16 + lrow) * CROW + kf * 32 + kg8];
#pragma unroll
  for (int s = 0; s < 2; s++)
#pragma unroll
    for (int kf = 0; kf < 7; kf++) af[s][kf] = pin8(af[s][kf]);  // no LDS remat

  const __bf16* wbase = wsb + lane * 8;

  for (int nf = 0; nf < 14; nf++) {
    const int col = nf * 16 + lrow;
    const float bt = Htb[col], bg = Hgb[col];
    f32x4 aT0 = {bt, bt, bt, bt}, aT1 = aT0;
    f32x4 aG0 = {bg, bg, bg, bg}, aG1 = aG0;
    const __bf16* wt = wbase + WT + ((nf * 7) << 9);
    const __bf16* wg = wbase + WG + ((nf * 7) << 9);
#pragma unroll
    for (int kf = 0; kf < 7; kf++) {
      bf16x8 wTv = *(const bf16x8*)(wt + (kf << 9));
      bf16x8 wGv = *(const bf16x8*)(wg + (kf << 9));
      aT0 = __builtin_amdgcn_mfma_f32_16x16x32_bf16(af[0][kf], wTv, aT0, 0, 0, 0);
      aT1 = __builtin_amdgcn_mfma_f32_16x16x32_bf16(af[1][kf], wTv, aT1, 0, 0, 0);
      aG0 = __builtin_amdgcn_mfma_f32_16x16x32_bf16(af[0][kf], wGv, aG0, 0, 0, 0);
      aG1 = __builtin_amdgcn_mfma_f32_16x16x32_bf16(af[1][kf], wGv, aG1, 0, 0, 0);
    }
#pragma unroll
    for (int s = 0; s < 2; s++) {
      f32x4 aT = s ? aT1 : aT0;
      f32x4 aG = s ? aG1 : aG0;
#pragma unroll
      for (int r = 0; r < 4; r++) {
        int row = rbase + s * 16 + rr0 + r;
        float t  = fmaxf(aT[r], 0.f);
        float gg = 1.f / (1.f + __expf(-aG[r]));
        float cv = (float)cnn[row * CROW + col];
        cnn[row * CROW + col] = (__bf16)(cv + gg * (t - cv));   // own rows only
      }
    }
  }

  // ---- phase 3: projection (P hi+lo), same wave rows; no barrier ----
  bf16x8 ah[2][7];
#pragma unroll
  for (int s = 0; s < 2; s++)
#pragma unroll
    for (int kf = 0; kf < 7; kf++)
      ah[s][kf] = *(const bf16x8*)&cnn[(rbase + s * 16 + lrow) * CROW + kf * 32 + kg8];

  for (int nf = 0; nf < 4; nf++) {
    const int col = nf * 16 + lrow;
    const float bp = Pb[col];
    f32x4 ac0 = {bp, bp, bp, bp}, ac1 = ac0;
    const __bf16* ph = wbase + WPHI + ((nf * 7) << 9);
    const __bf16* pl = wbase + WPLO + ((nf * 7) << 9);
#pragma unroll
    for (int kf = 0; kf < 7; kf++) {
      bf16x8 wh = *(const bf16x8*)(ph + (kf << 9));
      bf16x8 wl = *(const bf16x8*)(pl + (kf << 9));
      ac0 = __builtin_amdgcn_mfma_f32_16x16x32_bf16(ah[0][kf], wh, ac0, 0, 0, 0);
      ac1 = __builtin_amdgcn_mfma_f32_16x16x32_bf16(ah[1][kf], wh, ac1, 0, 0, 0);
      ac0 = __builtin_amdgcn_mfma_f32_16x16x32_bf16(ah[0][kf], wl, ac0, 0, 0, 0);
      ac1 = __builtin_amdgcn_mfma_f32_16x16x32_bf16(ah[1][kf], wl, ac1, 0, 0, 0);
    }
#pragma unroll
    for (int s = 0; s < 2; s++) {
      f32x4 ac = s ? ac1 : ac0;
#pragma unroll
      for (int r = 0; r < 4; r++) {
        int row = rbase + s * 16 + rr0 + r;
        if (tok0 + row < n_tok) out[(size_t)(tok0 + row) * 64 + col] = ac[r];
      }
    }
  }
}

extern "C" void kernel_launch(void* const* d_in, const int* in_sizes, int n_in,
                              void* d_out, int out_size, void* d_ws, size_t ws_size,
                              hipStream_t stream) {
  const int*   ids = (const int*)d_in[0];
  const float* E   = (const float*)d_in[1];
  const float* W1  = (const float*)d_in[2];
  const float* b1  = (const float*)d_in[3];
  const float* W2  = (const float*)d_in[4];
  const float* b2  = (const float*)d_in[5];
  const float* W3  = (const float*)d_in[6];
  const float* b3  = (const float*)d_in[7];
  const float* HtW = (const float*)d_in[8];
  const float* Htb = (const float*)d_in[9];
  const float* HgW = (const float*)d_in[10];
  const float* Hgb = (const float*)d_in[11];
  const float* PW  = (const float*)d_in[12];
  const float* Pb  = (const float*)d_in[13];
  float* out = (float*)d_out;
  unsigned short* tab = (unsigned short*)d_ws;
  __bf16* wsb = (__bf16*)((char*)d_ws + WOFFB);

  const int n_tok = in_sizes[0] / 20;
  prep_kernel<<<WSPLIT_BLOCKS + LUT_BLOCKS, 256, 0, stream>>>(
      E, W1, b1, W2, b2, W3, b3, HtW, HgW, PW, tab, wsb);
  cnn_kernel<<<(n_tok + 127) / 128, 256, 0, stream>>>(
      ids, tab, wsb, Htb, Hgb, Pb, out, n_tok);
}

// Round 9
// 48.318 us; speedup vs baseline: 1.1242x; 1.1242x over previous
//
#include <hip/hip_runtime.h>

// CharacterCNN — f32 in/out, int32 ids.
//  A) prep_kernel: [blocks 0..447] split Ht/Hg (hi bf16) + P (hi+lo bf16)
//     into CHUNK-major MFMA-fragment-linear layout (28,672-B chunks = 2 nf);
//     [blocks 448..451] conv pattern LUTs -> monotone-u16-key tables.
//  B) cnn_kernel: 256 thr / 64 tokens, wave owns 16 tokens (M-split).
//     masks -> key-table conv max (ReLU clamp) -> phase2: 7 chunks of
//     {reg-stage 28KB weights -> LDS wbuf; barrier; 2 nf MFMA from ds_read;
//     in-place hw epilogue; barrier} -> phase3: 2 P-chunks same -> f32 out.
//     Biases preloaded to registers. af pinned (no LDS remat).

typedef __attribute__((ext_vector_type(8))) __bf16 bf16x8;
typedef __attribute__((ext_vector_type(8))) unsigned short u16x8;
typedef __attribute__((ext_vector_type(4))) float f32x4;

// table element offsets (u16 units) within ws
#define LC1   0      // 3 x 32
#define LRAW2 96     // 9 x 64
#define LT2   672    // 16 x 64
#define LRAW3 1696   // 27 x 128
#define LT3LO 5152   // 16 x 128
#define LT3HI 7200   // 16 x 128
// bf16 weights start at WOFFB bytes. Element layout (bf16 units):
//   TG chunk c (c=0..6, nf=2c,2c+1): base c*14336
//     frag fi = isG*14 + (nf&1)*7 + kf   (fi*512 + lane*8 + j)
//   P  chunk c (c=0..1, nf=2c,2c+1): base 100352 + c*14336
//     frag fi = isLO*14 + (nf&1)*7 + kf
#define WOFFB 18944
#define PBASE 100352
#define NWTH  114688
#define WSPLIT_BLOCKS 448
#define LUT_BLOCKS 4
#define CROW 232      // cnn LDS row stride (bf16 elems)

__device__ __forceinline__ unsigned short keyf(float x) {
  __bf16 h = (__bf16)x;
  unsigned short b = __builtin_bit_cast(unsigned short, h);
  return (b & 0x8000) ? (unsigned short)~b : (unsigned short)(b | 0x8000);
}

__device__ __forceinline__ u16x8 kmax8(u16x8 a, u16x8 b) {
  return __builtin_elementwise_max(a, b);
}

__device__ __forceinline__ u16x8 splat8(unsigned short v) {
  u16x8 r = {v, v, v, v, v, v, v, v};
  return r;
}

__device__ __forceinline__ bf16x8 unmap8(u16x8 k) {
  union { u16x8 v; unsigned u[4]; } a; a.v = k;
  union { unsigned u[4]; bf16x8 v; } o;
#pragma unroll
  for (int i = 0; i < 4; i++) {
    unsigned kk = a.u[i];
    unsigned s = (kk & 0x80008000u) >> 15;
    o.u[i] = kk ^ ~(s * 0x7FFFu);
  }
  return o.v;
}

__device__ __forceinline__ bf16x8 pin8(bf16x8 v) {
  union { bf16x8 v; unsigned w[4]; } x; x.v = v;
  asm volatile("" : "+v"(x.w[0]), "+v"(x.w[1]), "+v"(x.w[2]), "+v"(x.w[3]) :: "memory");
  return x.v;
}

// ---------------- prep kernel ----------------
__global__ __launch_bounds__(256) void prep_kernel(
    const float* __restrict__ E,
    const float* __restrict__ W1, const float* __restrict__ b1,
    const float* __restrict__ W2, const float* __restrict__ b2,
    const float* __restrict__ W3, const float* __restrict__ b3,
    const float* __restrict__ HtW, const float* __restrict__ HgW,
    const float* __restrict__ PW,
    unsigned short* __restrict__ tab, __bf16* __restrict__ wsb)
{
  const int tid = threadIdx.x;
  if (blockIdx.x < WSPLIT_BLOCKS) {
    int idx = blockIdx.x * 256 + tid;
    if (idx < NWTH) {
      int e, isG = 0, isP = 0;
      if (idx < 50176)        { e = idx; }
      else if (idx < 100352)  { e = idx - 50176; isG = 1; }
      else                    { e = idx - 100352; isP = 1; }
      int col = e / 224, k = e - col * 224;
      int nf = col >> 4, kf = k >> 5, kr = k & 31;
      int lane = (col & 15) + ((kr >> 3) << 4), j = kr & 7;
      int c = nf >> 1;
      if (!isP) {
        int off = c * 14336 + (isG * 14 + (nf & 1) * 7 + kf) * 512 + lane * 8 + j;
        wsb[off] = (__bf16)(isG ? HgW[e] : HtW[e]);
      } else {
        float w = PW[e];
        __bf16 hi = (__bf16)w;
        int off = PBASE + c * 14336 + ((nf & 1) * 7 + kf) * 512 + lane * 8 + j;
        wsb[off] = hi;
        wsb[off + 7168] = (__bf16)(w - (float)hi);   // lo frags at +14*512
      }
    }
    return;
  }

  // ---- LUT part ----
  __shared__ float X[3][16];
  __shared__ float U1[3][32];
  __shared__ float U2[9][64];
  __shared__ float U3[27][128];
  const int gid = (blockIdx.x - WSPLIT_BLOCKS) * 256 + tid;
  const int gsz = LUT_BLOCKS * 256;
  if (tid < 48) { int s = tid >> 4, i = tid & 15; X[s][i] = (s == 0) ? 0.f : E[(s - 1) * 16 + i]; }
  __syncthreads();

  for (int idx = tid; idx < 96; idx += 256) {
    int s = idx >> 5, c = idx & 31;
    float acc = b1[c];
#pragma unroll
    for (int i = 0; i < 16; i++) acc += W1[c * 16 + i] * X[s][i];
    U1[s][c] = acc;
  }
  for (int idx = tid; idx < 576; idx += 256) {
    int p = idx >> 6, c = idx & 63;
    int sa = p / 3, sb = p % 3;
    float acc = b2[c];
#pragma unroll
    for (int i = 0; i < 16; i++)
      acc += W2[c * 32 + i * 2 + 0] * X[sa][i] + W2[c * 32 + i * 2 + 1] * X[sb][i];
    U2[p][c] = acc;
  }
  for (int idx = tid; idx < 3456; idx += 256) {
    int p = idx >> 7, c = idx & 127;
    int sa = p / 9, sb = (p / 3) % 3, sc = p % 3;
    float acc = b3[c];
#pragma unroll
    for (int i = 0; i < 16; i++)
      acc += W3[c * 48 + i * 3 + 0] * X[sa][i]
           + W3[c * 48 + i * 3 + 1] * X[sb][i]
           + W3[c * 48 + i * 3 + 2] * X[sc][i];
    U3[p][c] = acc;
  }
  __syncthreads();

  for (int idx = gid; idx < 96; idx += gsz) {
    int r = idx >> 5, c = idx & 31;
    float v = (r == 0) ? fmaxf(U1[1][c], U1[2][c]) : U1[r][c];
    tab[LC1 + idx] = keyf(v);
  }
  for (int idx = gid; idx < 576; idx += gsz) tab[LRAW2 + idx] = keyf(U2[idx >> 6][idx & 63]);
  for (int idx = gid; idx < 3456; idx += gsz) tab[LRAW3 + idx] = keyf(U3[idx >> 7][idx & 127]);
  for (int idx = gid; idx < 1024; idx += gsz) {
    int s = idx >> 6, c = idx & 63;
    unsigned short k = 0;
#pragma unroll
    for (int b = 0; b < 4; b++)
      if ((s >> b) & 1) { unsigned short kb = keyf(U2[4 + 3 * (b >> 1) + (b & 1)][c]); if (kb > k) k = kb; }
    tab[LT2 + idx] = k;
  }
  for (int idx = gid; idx < 2048; idx += gsz) {
    int s = idx >> 7, c = idx & 127;
    unsigned short k = 0;
#pragma unroll
    for (int b = 0; b < 4; b++)
      if ((s >> b) & 1) { unsigned short kb = keyf(U3[13 + 3 * (b >> 1) + (b & 1)][c]); if (kb > k) k = kb; }
    tab[LT3LO + idx] = k;
    k = 0;
#pragma unroll
    for (int b = 0; b < 4; b++)
      if ((s >> b) & 1) { unsigned short kb = keyf(U3[22 + 3 * (b >> 1) + (b & 1)][c]); if (kb > k) k = kb; }
    tab[LT3HI + idx] = k;
  }
}

// ------------- cnn kernel: LDS-staged weights, chunked -------------
__global__ __launch_bounds__(256) void cnn_kernel(
    const int* __restrict__ ids,
    const unsigned short* __restrict__ tab, const __bf16* __restrict__ wsb,
    const float* __restrict__ Htb, const float* __restrict__ Hgb,
    const float* __restrict__ Pb,
    float* __restrict__ out, int n_tok)
{
  __shared__ __attribute__((aligned(16))) __bf16 cnn[64 * CROW];   // 29,696 B
  __shared__ __attribute__((aligned(16))) __bf16 wbuf[14336];      // 28,672 B
  __shared__ unsigned masks[64][2];

  const int tid = threadIdx.x;
  const int wave = tid >> 6, lane = tid & 63;
  const int tok0 = blockIdx.x * 64;
  const int rbase = wave * 16;

  // ---- masks: lanes 0..15 compute own wave's 16 tokens ----
  if (lane < 16) {
    int row = rbase + lane;
    unsigned mw = 0, mb = 0;
    if (tok0 + row < n_tok) {
      const int4* idp4 = (const int4*)(ids + (size_t)(tok0 + row) * 20);
      int st[22]; st[0] = 0; st[21] = 0;
#pragma unroll
      for (int q = 0; q < 5; q++) {
        int4 v = idp4[q];
        st[q * 4 + 1] = v.x + 1; st[q * 4 + 2] = v.y + 1;
        st[q * 4 + 3] = v.z + 1; st[q * 4 + 4] = v.w + 1;
      }
      unsigned m3i = 0, m2i = 0, mchar = 0;
#pragma unroll
      for (int l = 1; l <= 18; l++) m3i |= 1u << ((st[l] - 1) * 4 + (st[l + 1] - 1) * 2 + (st[l + 2] - 1));
#pragma unroll
      for (int l = 1; l <= 19; l++) m2i |= 1u << ((st[l] - 1) * 2 + (st[l + 1] - 1));
#pragma unroll
      for (int l = 1; l <= 20; l++) mchar |= 1u << (st[l] - 1);
      int sel = (mchar == 3u) ? 0 : ((mchar & 1u) ? 1 : 2);
      mw = m3i | (m2i << 8) | ((unsigned)sel << 12);
      mb = (unsigned)st[1] | ((unsigned)(st[20] * 3) << 4)
         | ((unsigned)(st[1] * 3 + st[2]) << 8) | ((unsigned)(st[19] * 9 + st[20] * 3) << 16);
    }
    masks[row][0] = mw; masks[row][1] = mb;
  }
  // same-wave LDS write->read ordering via lgkmcnt

  // ---- phase 1: wave fills its own 16 cnn rows ----
  const u16x8 KZ = splat8(0x8000);
  {
    const int tl = lane >> 2, q = lane & 3;
    const int row = rbase + tl;
    const unsigned mw = masks[row][0], mb = masks[row][1];
    const int sel = (mw >> 12) & 3;
    {
      u16x8 v = *(const u16x8*)(tab + LC1 + sel * 32 + q * 8);
      *(bf16x8*)&cnn[row * CROW + q * 8] = unmap8(kmax8(v, KZ));
    }
#pragma unroll
    for (int jj = 0; jj < 2; jj++) {
      int g = q + jj * 4;
      u16x8 v = *(const u16x8*)(tab + LT2 + ((mw >> 8) & 15) * 64 + g * 8);
      v = kmax8(v, *(const u16x8*)(tab + LRAW2 + (mb & 15) * 64 + g * 8));
      v = kmax8(v, *(const u16x8*)(tab + LRAW2 + ((mb >> 4) & 15) * 64 + g * 8));
      *(bf16x8*)&cnn[row * CROW + 32 + g * 8] = unmap8(kmax8(v, KZ));
    }
    const int m3 = mw & 255;
#pragma unroll
    for (int jj = 0; jj < 4; jj++) {
      int g = q + jj * 4;
      u16x8 v = kmax8(*(const u16x8*)(tab + LT3LO + (m3 & 15) * 128 + g * 8),
                      *(const u16x8*)(tab + LT3HI + ((m3 >> 4) & 15) * 128 + g * 8));
      v = kmax8(v, *(const u16x8*)(tab + LRAW3 + ((mb >> 8) & 15) * 128 + g * 8));
      v = kmax8(v, *(const u16x8*)(tab + LRAW3 + ((mb >> 16) & 31) * 128 + g * 8));
      *(bf16x8*)&cnn[row * CROW + 96 + g * 8] = unmap8(kmax8(v, KZ));
    }
  }

  // ---- A-fragments + bias preload ----
  const int lrow = lane & 15;
  const int kg8 = (lane >> 4) * 8;
  const int rr0 = (lane >> 4) * 4;

  bf16x8 af[7];
#pragma unroll
  for (int kf = 0; kf < 7; kf++)
    af[kf] = *(const bf16x8*)&cnn[(rbase + lrow) * CROW + kf * 32 + kg8];
#pragma unroll
  for (int kf = 0; kf < 7; kf++) af[kf] = pin8(af[kf]);   // no LDS remat

  float btv[14], bgv[14], bpv[4];
#pragma unroll
  for (int nf = 0; nf < 14; nf++) {
    btv[nf] = Htb[nf * 16 + lrow];
    bgv[nf] = Hgb[nf * 16 + lrow];
  }
#pragma unroll
  for (int nf = 0; nf < 4; nf++) bpv[nf] = Pb[nf * 16 + lrow];

  // ---- phase 2: 7 chunks of {stage 2-nf weights; barrier; compute; barrier} ----
#pragma unroll
  for (int c = 0; c < 7; c++) {
    {
      bf16x8 stg[7];
#pragma unroll
      for (int r = 0; r < 7; r++)
        stg[r] = *(const bf16x8*)(wsb + c * 14336 + r * 2048 + tid * 8);
#pragma unroll
      for (int r = 0; r < 7; r++)
        *(bf16x8*)&wbuf[r * 2048 + tid * 8] = stg[r];
    }
    __syncthreads();
#pragma unroll
    for (int i = 0; i < 2; i++) {
      const int nf = c * 2 + i;
      const int col = nf * 16 + lrow;
      const float bt = btv[nf], bg = bgv[nf];
      f32x4 aT = {bt, bt, bt, bt};
      f32x4 aG = {bg, bg, bg, bg};
#pragma unroll
      for (int kf = 0; kf < 7; kf++) {
        bf16x8 wTv = *(const bf16x8*)&wbuf[(i * 7 + kf) * 512 + lane * 8];
        bf16x8 wGv = *(const bf16x8*)&wbuf[(14 + i * 7 + kf) * 512 + lane * 8];
        aT = __builtin_amdgcn_mfma_f32_16x16x32_bf16(af[kf], wTv, aT, 0, 0, 0);
        aG = __builtin_amdgcn_mfma_f32_16x16x32_bf16(af[kf], wGv, aG, 0, 0, 0);
      }
#pragma unroll
      for (int r = 0; r < 4; r++) {
        int row = rbase + rr0 + r;
        float t  = fmaxf(aT[r], 0.f);
        float gg = 1.f / (1.f + __expf(-aG[r]));
        float cv = (float)cnn[row * CROW + col];
        cnn[row * CROW + col] = (__bf16)(cv + gg * (t - cv));   // own rows only
      }
    }
    __syncthreads();
  }

  // ---- phase 3: hw A-frags, then 2 P-chunks (hi+lo) ----
  bf16x8 ah[7];
#pragma unroll
  for (int kf = 0; kf < 7; kf++)
    ah[kf] = *(const bf16x8*)&cnn[(rbase + lrow) * CROW + kf * 32 + kg8];
#pragma unroll
  for (int kf = 0; kf < 7; kf++) ah[kf] = pin8(ah[kf]);

#pragma unroll
  for (int c = 0; c < 2; c++) {
    {
      bf16x8 stg[7];
#pragma unroll
      for (int r = 0; r < 7; r++)
        stg[r] = *(const bf16x8*)(wsb + PBASE + c * 14336 + r * 2048 + tid * 8);
#pragma unroll
      for (int r = 0; r < 7; r++)
        *(bf16x8*)&wbuf[r * 2048 + tid * 8] = stg[r];
    }
    __syncthreads();
#pragma unroll
    for (int i = 0; i < 2; i++) {
      const int nf = c * 2 + i;
      const int col = nf * 16 + lrow;
      const float bp = bpv[nf];
      f32x4 ac = {bp, bp, bp, bp};
#pragma unroll
      for (int kf = 0; kf < 7; kf++) {
        bf16x8 wh = *(const bf16x8*)&wbuf[(i * 7 + kf) * 512 + lane * 8];
        bf16x8 wl = *(const bf16x8*)&wbuf[(14 + i * 7 + kf) * 512 + lane * 8];
        ac = __builtin_amdgcn_mfma_f32_16x16x32_bf16(ah[kf], wh, ac, 0, 0, 0);
        ac = __builtin_amdgcn_mfma_f32_16x16x32_bf16(ah[kf], wl, ac, 0, 0, 0);
      }
#pragma unroll
      for (int r = 0; r < 4; r++) {
        int row = rbase + rr0 + r;
        if (tok0 + row < n_tok) out[(size_t)(tok0 + row) * 64 + col] = ac[r];
      }
    }
    __syncthreads();
  }
}

extern "C" void kernel_launch(void* const* d_in, const int* in_sizes, int n_in,
                              void* d_out, int out_size, void* d_ws, size_t ws_size,
                              hipStream_t stream) {
  const int*   ids = (const int*)d_in[0];
  const float* E   = (const float*)d_in[1];
  const float* W1  = (const float*)d_in[2];
  const float* b1  = (const float*)d_in[3];
  const float* W2  = (const float*)d_in[4];
  const float* b2  = (const float*)d_in[5];
  const float* W3  = (const float*)d_in[6];
  const float* b3  = (const float*)d_in[7];
  const float* HtW = (const float*)d_in[8];
  const float* Htb = (const float*)d_in[9];
  const float* HgW = (const float*)d_in[10];
  const float* Hgb = (const float*)d_in[11];
  const float* PW  = (const float*)d_in[12];
  const float* Pb  = (const float*)d_in[13];
  float* out = (float*)d_out;
  unsigned short* tab = (unsigned short*)d_ws;
  __bf16* wsb = (__bf16*)((char*)d_ws + WOFFB);

  const int n_tok = in_sizes[0] / 20;
  prep_kernel<<<WSPLIT_BLOCKS + LUT_BLOCKS, 256, 0, stream>>>(
      E, W1, b1, W2, b2, W3, b3, HtW, HgW, PW, tab, wsb);
  cnn_kernel<<<(n_tok + 63) / 64, 256, 0, stream>>>(
      ids, tab, wsb, Htb, Hgb, Pb, out, n_tok);
}